// Round 3
// baseline (94.979 us; speedup 1.0000x reference)
//
#include <hip/hip_runtime.h>
#include <hip/hip_bf16.h>
#include <stdint.h>
#include <stddef.h>

// ---------------------------------------------------------------------------
// MyConv2D fixed-point conv (Width=8), valid 3x3, NHWC, + bias + ReLU.
// R3: 8-phase-style deep pipeline (T3+T4+T5). BM=128 BN=256 BK=64, 512 thr
// (8 waves, 2x4, 64x64/wave), triple-buffered LDS (144 KB), counted vmcnt(6),
// inline-asm ds_read_b128 with XOR swizzle (0 conflicts, verified R2),
// global_load_lds width-16 staging, setprio around MFMA clusters.
// Exactness: quantized values a/256, |a|<=256 (bf16-exact); partial sums are
// integer multiples of 2^-16 << 2^24 -> fp32 MFMA accumulation exact.
// ---------------------------------------------------------------------------

typedef float  f32x4  __attribute__((ext_vector_type(4)));
typedef short  bf16x8 __attribute__((ext_vector_type(8)));

#define N_IMG 32
#define H_IN 56
#define W_IN 56
#define C_IN 128
#define F_OUT 256
#define OHW 54
#define M_TOTAL (N_IMG * OHW * OHW)   // 93312 = 729 * 128
#define BM 128
#define BN 256
#define BK 64
#define NTILES 18                      // K = 9 taps * 128c = 1152 = 18 * 64
#define A_BUF_SHORTS (BM * BK)         // 8192  (16 KB)
#define B_BUF_SHORTS (BN * BK)         // 16384 (32 KB)
#define A_BUF_BYTES (A_BUF_SHORTS * 2)
#define B_BUF_BYTES (B_BUF_SHORTS * 2)

__device__ __forceinline__ unsigned short quant_to_bf16(float x) {
    float a = rintf(x * 256.0f);                 // half-to-even == jnp.round
    a = fminf(fmaxf(a, -256.0f), 256.0f);
    float q = a * 0.00390625f;                   // exact in bf16
    union { float f; unsigned int u; } cv; cv.f = q;
    return (unsigned short)(cv.u >> 16);
}

__device__ __forceinline__ void async_copy16(const unsigned short* g, unsigned short* l) {
    __builtin_amdgcn_global_load_lds(
        (const __attribute__((address_space(1))) unsigned int*)g,
        (__attribute__((address_space(3))) unsigned int*)l, 16, 0, 0);
}

__device__ __forceinline__ unsigned lds_off(const void* p) {
    return (unsigned)(uintptr_t)(__attribute__((address_space(3))) const void*)p;
}

__device__ __forceinline__ bf16x8 lds_read_b128(unsigned addr) {
    bf16x8 r;
    asm volatile("ds_read_b128 %0, %1" : "=v"(r) : "v"(addr));
    return r;
}

__global__ __launch_bounds__(256) void quant_x_kernel(
        const float* __restrict__ x, unsigned short* __restrict__ xq) {
    int i = (blockIdx.x * 256 + threadIdx.x) * 4;
    float4 v = *reinterpret_cast<const float4*>(x + i);
    ushort4 o;
    o.x = quant_to_bf16(v.x);
    o.y = quant_to_bf16(v.y);
    o.z = quant_to_bf16(v.z);
    o.w = quant_to_bf16(v.w);
    *reinterpret_cast<ushort4*>(xq + i) = o;
}

// w (3,3,128,256) -> wp[kk][f=256][c=128] bf16 (B^T, K-contiguous)
__global__ __launch_bounds__(256) void quant_w_kernel(
        const float* __restrict__ w, unsigned short* __restrict__ wp) {
    int idx = blockIdx.x * 256 + threadIdx.x;
    int c  = idx & 127;
    int f  = (idx >> 7) & 255;
    int kk = idx >> 15;
    wp[idx] = quant_to_bf16(w[(kk * C_IN + c) * F_OUT + f]);
}

__global__ __launch_bounds__(512, 2) void conv_kernel(
        const unsigned short* __restrict__ xq,   // [32][56][56][128] bf16
        const unsigned short* __restrict__ wp,   // [9][256][128] bf16
        const float* __restrict__ bias,          // [54][54][256]
        float* __restrict__ out)                 // [93312][256]
{
    __shared__ __attribute__((aligned(16))) unsigned short Alds[3][A_BUF_SHORTS]; // 48 KB
    __shared__ __attribute__((aligned(16))) unsigned short Blds[3][B_BUF_SHORTS]; // 96 KB

    const int tid  = threadIdx.x;
    const int lane = tid & 63;
    const int wave = tid >> 6;
    const int wr   = wave >> 2;   // 0..1
    const int wc   = wave & 3;    // 0..3
    const int m0   = blockIdx.x * BM;

    // ---- staging geometry: chunk = 512*r + tid; row = 64r + (tid>>3); c16 = tid&7
    const int rowt = tid >> 3;
    const int c16  = tid & 7;
    const int sw   = c16 ^ (rowt & 7);   // pre-swizzled global chunk (rule #21)
    const int dstc = tid & ~63;          // wave-uniform chunk base

    const unsigned short* a_src[2];
#pragma unroll
    for (int r = 0; r < 2; ++r) {
        int m = m0 + 64 * r + rowt;
        int n_img = m / (OHW * OHW);
        int rem   = m % (OHW * OHW);
        int oh = rem / OHW, ow = rem % OHW;
        a_src[r] = xq + (size_t)((n_img * H_IN + oh) * W_IN + ow) * C_IN + sw * 8;
    }
    const unsigned short* b_src[4];
#pragma unroll
    for (int r = 0; r < 4; ++r)
        b_src[r] = wp + (size_t)(64 * r + rowt) * C_IN + sw * 8;

    // ---- ds_read addresses (byte offsets in LDS), buffer 0; add cur*stride at use
    const int mr = lane & 15;
    const int lq = lane >> 4;
    unsigned a_rd[4][2], b_rd[4][2];
    const unsigned Abase = lds_off(&Alds[0][0]);
    const unsigned Bbase = lds_off(&Blds[0][0]);
#pragma unroll
    for (int mi = 0; mi < 4; ++mi)
#pragma unroll
        for (int ks = 0; ks < 2; ++ks) {
            int row = wr * 64 + mi * 16 + mr;
            int ch  = (ks * 4 + lq) ^ (mr & 7);
            a_rd[mi][ks] = Abase + row * (BK * 2) + ch * 16;
        }
#pragma unroll
    for (int ni = 0; ni < 4; ++ni)
#pragma unroll
        for (int ks = 0; ks < 2; ++ks) {
            int row = wc * 64 + ni * 16 + mr;
            int ch  = (ks * 4 + lq) ^ (mr & 7);
            b_rd[ni][ks] = Bbase + row * (BK * 2) + ch * 16;
        }

    f32x4 acc[4][4];
#pragma unroll
    for (int i = 0; i < 4; ++i)
#pragma unroll
        for (int j = 0; j < 4; ++j) acc[i][j] = (f32x4)(0.0f);

    // ---- staging issue helpers (tile tt -> buffer bi) ----
    auto stage_p0 = [&](int tt, int bi) {
        int kk = tt >> 1, half = tt & 1;
        int kh = (kk * 43) >> 7, kw = kk - 3 * kh;    // kk/3 for kk in [0,8]
        int aoff = (kh * W_IN + kw) * C_IN + half * 64;
        int boff = kk * (F_OUT * C_IN) + half * 64;
        async_copy16(a_src[0] + aoff, &Alds[bi][dstc * 8]);
        async_copy16(a_src[1] + aoff, &Alds[bi][(512 + dstc) * 8]);
        async_copy16(b_src[0] + boff, &Blds[bi][dstc * 8]);
    };
    auto stage_p1 = [&](int tt, int bi) {
        int kk = tt >> 1, half = tt & 1;
        int boff = kk * (F_OUT * C_IN) + half * 64;
        async_copy16(b_src[1] + boff, &Blds[bi][(512 + dstc) * 8]);
        async_copy16(b_src[2] + boff, &Blds[bi][(1024 + dstc) * 8]);
        async_copy16(b_src[3] + boff, &Blds[bi][(1536 + dstc) * 8]);
    };

    // ---- one K-tile: 2 phases, counted end-wait ----
    // endmode: 0 = vmcnt(6)+barrier, 1 = vmcnt(0)+barrier, 2 = none (last tile)
    auto do_tile = [&](int cur, int stage_tt, bool dostage, int endmode) {
        const unsigned ca = (unsigned)cur * A_BUF_BYTES;
        const unsigned cb = (unsigned)cur * B_BUF_BYTES;
        int bi = cur + 2; if (bi >= 3) bi -= 3;       // (cur+2)%3

        // -------- phase 0: A frags + B cols 0,1 --------
        bf16x8 af[4][2], bq[2][2];
#pragma unroll
        for (int mi = 0; mi < 4; ++mi)
#pragma unroll
            for (int ks = 0; ks < 2; ++ks)
                af[mi][ks] = lds_read_b128(a_rd[mi][ks] + ca);
#pragma unroll
        for (int ni = 0; ni < 2; ++ni)
#pragma unroll
            for (int ks = 0; ks < 2; ++ks)
                bq[ni][ks] = lds_read_b128(b_rd[ni][ks] + cb);
        if (dostage) stage_p0(stage_tt, bi);
        asm volatile("" ::: "memory");
        __builtin_amdgcn_s_barrier();
        asm volatile("s_waitcnt lgkmcnt(0)" ::: "memory");
        __builtin_amdgcn_sched_barrier(0);            // rule #18
        __builtin_amdgcn_s_setprio(1);
#pragma unroll
        for (int mi = 0; mi < 4; ++mi)
#pragma unroll
            for (int ni = 0; ni < 2; ++ni)
#pragma unroll
                for (int ks = 0; ks < 2; ++ks)
                    acc[mi][ni] = __builtin_amdgcn_mfma_f32_16x16x32_bf16(
                        af[mi][ks], bq[ni][ks], acc[mi][ni], 0, 0, 0);
        __builtin_amdgcn_s_setprio(0);
        asm volatile("" ::: "memory");
        __builtin_amdgcn_s_barrier();

        // -------- phase 1: B cols 2,3 (A frags reused from regs) --------
#pragma unroll
        for (int ni = 0; ni < 2; ++ni)
#pragma unroll
            for (int ks = 0; ks < 2; ++ks)
                bq[ni][ks] = lds_read_b128(b_rd[ni + 2][ks] + cb);
        if (dostage) stage_p1(stage_tt, bi);
        asm volatile("" ::: "memory");
        __builtin_amdgcn_s_barrier();
        asm volatile("s_waitcnt lgkmcnt(0)" ::: "memory");
        __builtin_amdgcn_sched_barrier(0);
        __builtin_amdgcn_s_setprio(1);
#pragma unroll
        for (int mi = 0; mi < 4; ++mi)
#pragma unroll
            for (int ni = 0; ni < 2; ++ni)
#pragma unroll
                for (int ks = 0; ks < 2; ++ks)
                    acc[mi][ni + 2] = __builtin_amdgcn_mfma_f32_16x16x32_bf16(
                        af[mi][ks], bq[ni][ks], acc[mi][ni + 2], 0, 0, 0);
        __builtin_amdgcn_s_setprio(0);
        if (endmode == 0)      asm volatile("s_waitcnt vmcnt(6)" ::: "memory");
        else if (endmode == 1) asm volatile("s_waitcnt vmcnt(0)" ::: "memory");
        if (endmode <= 1) {
            asm volatile("" ::: "memory");
            __builtin_amdgcn_s_barrier();
        }
    };

    // ---- prologue: stage tiles 0,1 (12 loads); wait tile 0 (6 newest remain) ----
    stage_p0(0, 0); stage_p1(0, 0);    // NOTE: bi arg abused: write buf 0
    stage_p0(1, 1); stage_p1(1, 1);    // write buf 1
    asm volatile("s_waitcnt vmcnt(6)" ::: "memory");
    __builtin_amdgcn_s_barrier();

    // ---- main loop: steady state keeps 6-12 loads in flight, never drains ----
#pragma unroll 1
    for (int t = 0; t < 16; ++t) {
        int cur = t - (t / 3) * 3;                   // t % 3
        do_tile(cur, t + 2, true, 0);
    }
    do_tile(1, 0, false, 1);   // t=16: drain so tile 17 is landed
    do_tile(2, 0, false, 2);   // t=17: last tile, no end sync

    // ---- epilogue: quantize, bias, ReLU ----
    const int fcol0 = wc * 64 + mr;
#pragma unroll
    for (int mi = 0; mi < 4; ++mi) {
#pragma unroll
        for (int rr = 0; rr < 4; ++rr) {
            const int m = m0 + wr * 64 + mi * 16 + lq * 4 + rr;
            const float* brow = bias + (size_t)(m % (OHW * OHW)) * F_OUT;
            float* orow = out + (size_t)m * F_OUT;
#pragma unroll
            for (int ni = 0; ni < 4; ++ni) {
                float v = acc[mi][ni][rr];
                float t = rintf(v * 256.0f);
                t = fminf(fmaxf(t, -256.0f), 256.0f);
                float o = t * 0.00390625f + brow[fcol0 + ni * 16];
                orow[fcol0 + ni * 16] = fmaxf(o, 0.0f);
            }
        }
    }
}

extern "C" void kernel_launch(void* const* d_in, const int* in_sizes, int n_in,
                              void* d_out, int out_size, void* d_ws, size_t ws_size,
                              hipStream_t stream) {
    (void)in_sizes; (void)n_in; (void)out_size;
    const float* x    = (const float*)d_in[0];
    const float* w    = (const float*)d_in[1];
    const float* bias = (const float*)d_in[2];
    float* out        = (float*)d_out;

    const size_t x_elems = (size_t)N_IMG * H_IN * W_IN * C_IN;
    const size_t w_elems = (size_t)9 * F_OUT * C_IN;
    const size_t xq_bytes = x_elems * sizeof(unsigned short);
    const size_t need = xq_bytes + w_elems * sizeof(unsigned short);
    if (ws_size < need) return;

    unsigned short* xq = (unsigned short*)d_ws;
    unsigned short* wp = (unsigned short*)((char*)d_ws + xq_bytes);

    quant_x_kernel<<<(int)(x_elems / (256 * 4)), 256, 0, stream>>>(x, xq);
    quant_w_kernel<<<(int)(w_elems / 256), 256, 0, stream>>>(w, wp);
    conv_kernel<<<M_TOTAL / BM, 512, 0, stream>>>(xq, wp, bias, out);
}